// Round 6
// baseline (458.810 us; speedup 1.0000x reference)
//
#include <hip/hip_runtime.h>
#include <hip/hip_bf16.h>
#include <math.h>

// B=16, T=16, O=10, L=160, d=768, heads=12, dh=64, H=W=14, Tr=2.
// Out: (16, 8*196, 768) fp32.

#define BATCH 16
#define TT    16
#define OO    10
#define LL    160
#define BL    2560
#define DD    768
#define NH    12
#define DH    64
#define GH    14
#define GW    14
#define TGRP  8

typedef unsigned short ushort_t;
typedef __attribute__((ext_vector_type(8))) __bf16 bf16x8;
typedef __attribute__((ext_vector_type(4))) float f32x4;

__device__ __forceinline__ ushort_t f2bf(float f) {
    unsigned int u = __float_as_uint(f);
    u += 0x7fffu + ((u >> 16) & 1u);         // RNE
    return (ushort_t)(u >> 16);
}

// XCD chunk swizzle (T1): nwg % 8 == 0 for every launch using this.
__device__ __forceinline__ int swz_xcd(int bid, int nwg) {
    return (bid & 7) * (nwg >> 3) + (bid >> 3);
}

// ---------------------------------------------------------------------------
// 0) weight convert+transpose: W[K][N] fp32 -> Wt[N][K] bf16
// ---------------------------------------------------------------------------
__global__ __launch_bounds__(256)
void transpose_w(const float* __restrict__ W, ushort_t* __restrict__ Wt, int K, int N)
{
    __shared__ float s[32][33];
    const int n0 = blockIdx.x * 32, k0 = blockIdx.y * 32;
    const int tx = threadIdx.x & 31, ty = threadIdx.x >> 5;   // ty 0..7
#pragma unroll
    for (int r = 0; r < 4; ++r)
        s[ty + r * 8][tx] = W[(size_t)(k0 + ty + r * 8) * N + n0 + tx];
    __syncthreads();
#pragma unroll
    for (int r = 0; r < 4; ++r)
        Wt[(size_t)(n0 + ty + r * 8) * K + k0 + tx] = f2bf(s[tx][ty + r * 8]);
}

// ---------------------------------------------------------------------------
// 1a) box hidden: h = relu(box @ w1) -> bf16 [2560][384]
// ---------------------------------------------------------------------------
__global__ __launch_bounds__(256)
void box_h(const float* __restrict__ box, const float* __restrict__ w1,
           ushort_t* __restrict__ h)
{
    const int idx = blockIdx.x * 256 + threadIdx.x;     // 0..983039
    const int r = idx / 384, j = idx - r * 384;
    const float* bx = box + (size_t)r * 4;
    float v = bx[0] * w1[j] + bx[1] * w1[384 + j] +
              bx[2] * w1[768 + j] + bx[3] * w1[1152 + j];
    h[idx] = f2bf(fmaxf(v, 0.f));
}

// ---------------------------------------------------------------------------
// 2) LayerNorm -> bf16 output
// ---------------------------------------------------------------------------
__global__ __launch_bounds__(256)
void ln_kernel(const float* __restrict__ in, const float* __restrict__ g,
               const float* __restrict__ bvec, ushort_t* __restrict__ out)
{
    const int r = blockIdx.x;
    const int tid = threadIdx.x;
    const float* row = in + (size_t)r * DD;
    float v0 = row[tid], v1 = row[tid + 256], v2 = row[tid + 512];
    float s  = v0 + v1 + v2;
    float s2 = v0 * v0 + v1 * v1 + v2 * v2;
#pragma unroll
    for (int off = 32; off > 0; off >>= 1) {
        s  += __shfl_down(s, off);
        s2 += __shfl_down(s2, off);
    }
    __shared__ float red[8];
    int wave = tid >> 6, lane = tid & 63;
    if (lane == 0) { red[wave] = s; red[wave + 4] = s2; }
    __syncthreads();
    s  = red[0] + red[1] + red[2] + red[3];
    s2 = red[4] + red[5] + red[6] + red[7];
    float mu  = s * (1.f / DD);
    float var = s2 * (1.f / DD) - mu * mu;
    float inv = rsqrtf(var + 1e-5f);
    ushort_t* op = out + (size_t)r * DD;
    op[tid]       = f2bf((v0 - mu) * inv * g[tid]       + bvec[tid]);
    op[tid + 256] = f2bf((v1 - mu) * inv * g[tid + 256] + bvec[tid + 256]);
    op[tid + 512] = f2bf((v2 - mu) * inv * g[tid + 512] + bvec[tid + 512]);
}

// ---------------------------------------------------------------------------
// 3) unified register-fragment bf16 MFMA GEMM.
//    1 wave per block, tile (MI*16) x (NJ*16), no LDS, no barriers.
//    Small tiles -> many 1-wave blocks -> 2.8-3.75 waves/SIMD resident
//    (every prior structure ran at <=1.9 waves/SIMD and stalled at ~8%
//    MfmaUtil regardless of traffic/steps/atomics -> latency was never
//    hidden; this buys TLP at the cost of 2x operand re-reads, absorbed
//    by L2/L3).  XCD chunk-swizzle for L2 locality.
//    A[M][K] row-major bf16 (lda), Bt[N][K] row-major bf16 (ldb).
//    MODE 1: Cf += acc + bias       (single writer; SPLIT must be 1)
//    MODE 2: Cb = bf16(gelu(acc+bias))
//    MODE 3: Cb = bf16(acc)
//    MODE 4: Cf = relu(acc) + cat[(row%160)][col]
//    MODE 5: Cf[bz*BL*DD + idx] = acc   (split-K partials, NO atomics)
// ---------------------------------------------------------------------------
template <int MI, int NJ, int MODE, int SPLIT>
__global__ __launch_bounds__(64)
void gemm_rf2(const ushort_t* __restrict__ A, int lda,
              const ushort_t* __restrict__ Bt, int ldb,
              const float* __restrict__ bias, const float* __restrict__ cat,
              float* __restrict__ Cf, ushort_t* __restrict__ Cb,
              int ldc, int K)
{
    const int lane = threadIdx.x;
    const int l16 = lane & 15, quad = lane >> 4;

    const int nwg = gridDim.x * gridDim.y * gridDim.z;
    const int bid = blockIdx.x + gridDim.x * (blockIdx.y + gridDim.y * blockIdx.z);
    const int w   = swz_xcd(bid, nwg);
    const int bx  = w % gridDim.x;
    const int byz = w / gridDim.x;
    const int by  = byz % gridDim.y;
    const int bz  = byz / gridDim.y;

    const int row0 = by * (MI * 16), col0 = bx * (NJ * 16);
    const int Kper = K / SPLIT;                 // multiple of 64
    const int k0   = bz * Kper;

    const ushort_t* ap = A  + (size_t)(row0 + l16) * lda + k0 + quad * 8;
    const ushort_t* bp = Bt + (size_t)(col0 + l16) * ldb + k0 + quad * 8;

    f32x4 acc[MI][NJ];
#pragma unroll
    for (int i = 0; i < MI; ++i)
#pragma unroll
        for (int j = 0; j < NJ; ++j) {
            acc[i][j][0] = 0.f; acc[i][j][1] = 0.f;
            acc[i][j][2] = 0.f; acc[i][j][3] = 0.f;
        }

#define LOADF2(aa, bb, kk)                                                       \
    _Pragma("unroll")                                                            \
    for (int i = 0; i < MI; ++i)                                                 \
        aa[i] = *reinterpret_cast<const bf16x8*>(ap + (size_t)(i * 16) * lda + (kk)); \
    _Pragma("unroll")                                                            \
    for (int j = 0; j < NJ; ++j)                                                 \
        bb[j] = *reinterpret_cast<const bf16x8*>(bp + (size_t)(j * 16) * ldb + (kk));
#define MFMA2(aa, bb)                                                            \
    _Pragma("unroll")                                                            \
    for (int i = 0; i < MI; ++i)                                                 \
        _Pragma("unroll")                                                        \
        for (int j = 0; j < NJ; ++j)                                             \
            acc[i][j] = __builtin_amdgcn_mfma_f32_16x16x32_bf16(aa[i], bb[j], acc[i][j], 0, 0, 0);

    bf16x8 a0[MI], b0[NJ], a1[MI], b1[NJ];
    LOADF2(a0, b0, 0)
    int kt = 0;
    for (; kt + 64 < Kper; kt += 64) {
        LOADF2(a1, b1, kt + 32)
        MFMA2(a0, b0)
        LOADF2(a0, b0, kt + 64)
        MFMA2(a1, b1)
    }
    LOADF2(a1, b1, kt + 32)
    MFMA2(a0, b0)
    MFMA2(a1, b1)
#undef LOADF2
#undef MFMA2

    // epilogue: C/D layout col=lane&15, row=(lane>>4)*4+reg (HW-verified)
    const int q4 = quad * 4;
#pragma unroll
    for (int i = 0; i < MI; ++i)
#pragma unroll
        for (int j = 0; j < NJ; ++j) {
            const int gcol = col0 + j * 16 + l16;
            const float bj = (MODE == 1 || MODE == 2) ? bias[gcol] : 0.f;
#pragma unroll
            for (int r = 0; r < 4; ++r) {
                const int grow = row0 + i * 16 + q4 + r;
                const size_t idx = (size_t)grow * ldc + gcol;
                const float v = acc[i][j][r];
                if (MODE == 1) {
                    Cf[idx] += v + bj;                         // single writer
                } else if (MODE == 2) {
                    const float u = v + bj;
                    Cb[idx] = f2bf(0.5f * u * (1.f + erff(u * 0.70710678118654752f)));
                } else if (MODE == 3) {
                    Cb[idx] = f2bf(v);
                } else if (MODE == 4) {
                    Cf[idx] = fmaxf(v, 0.f) + cat[(size_t)(grow % LL) * DD + gcol];
                } else {                                       // MODE 5: partials
                    Cf[(size_t)bz * (BL * DD) + idx] = v;
                }
            }
        }
}

// ---------------------------------------------------------------------------
// 3c) split-K reduce for fc2: x += P0 + P1 + bias (pure streaming)
// ---------------------------------------------------------------------------
__global__ __launch_bounds__(256)
void reduce_fc2(const float* __restrict__ P, const float* __restrict__ bias,
                float* __restrict__ x)
{
    const int i4 = (blockIdx.x * 256 + threadIdx.x) * 4;    // 0..1966076
    f32x4 a  = *reinterpret_cast<const f32x4*>(&x[i4]);
    f32x4 p0 = *reinterpret_cast<const f32x4*>(&P[i4]);
    f32x4 p1 = *reinterpret_cast<const f32x4*>(&P[BL * DD + i4]);
    f32x4 b  = *reinterpret_cast<const f32x4*>(&bias[i4 % DD]);
    a = a + p0 + p1 + b;
    *reinterpret_cast<f32x4*>(&x[i4]) = a;
}

// ---------------------------------------------------------------------------
// 4) MFMA attention: block per (b,head), 5 waves; output written back into
//    the (dead) q-slot of qkv. Frag layouts HW-verified by gemm path.
// ---------------------------------------------------------------------------
#define KS_STRIDE 72
#define VT_STRIDE 168
__global__ __launch_bounds__(320)
void attention_mfma(ushort_t* __restrict__ qkv)
{
    __shared__ ushort_t Ks[160 * KS_STRIDE];
    __shared__ ushort_t Vt[64 * VT_STRIDE];
    __shared__ ushort_t Pb[5][32 * VT_STRIDE];

    const int b  = blockIdx.x / NH;
    const int hh = blockIdx.x % NH;
    ushort_t* basew = qkv + (size_t)b * LL * (3 * DD) + hh * DH;
    const ushort_t* base = basew;
    const int tid  = threadIdx.x;
    const int wave = tid >> 6, lane = tid & 63;
    const int l16 = lane & 15, quad = lane >> 4;

    // ---- stage K rows and V transposed ----
#pragma unroll
    for (int it = 0; it < 4; ++it) {
        int idx = tid + it * 320;                 // 0..1279
        int l = idx >> 3, c8 = (idx & 7) * 8;
        uint4 kv = *(const uint4*)(base + (size_t)l * (3 * DD) + DD + c8);
        *(uint4*)&Ks[l * KS_STRIDE + c8] = kv;
        uint4 vv = *(const uint4*)(base + (size_t)l * (3 * DD) + 2 * DD + c8);
        ushort_t e[8];
        *(uint4*)e = vv;
#pragma unroll
        for (int i = 0; i < 8; ++i)
            Vt[(c8 + i) * VT_STRIDE + l] = e[i];
    }

    // ---- Q fragments straight from global ----
    const int q0 = wave * 32;
    bf16x8 qf[2][2];
#pragma unroll
    for (int t = 0; t < 2; ++t)
#pragma unroll
        for (int k = 0; k < 2; ++k)
            qf[t][k] = *reinterpret_cast<const bf16x8*>(
                base + (size_t)(q0 + t * 16 + l16) * (3 * DD) + k * 32 + quad * 8);

    __syncthreads();

    // ---- S = QK^T ----
    f32x4 S0[10], S1[10];
#pragma unroll
    for (int nt = 0; nt < 10; ++nt) {
        f32x4 z = {0.f, 0.f, 0.f, 0.f};
        const ushort_t* kb = &Ks[(nt * 16 + l16) * KS_STRIDE + quad * 8];
        bf16x8 kf0 = *reinterpret_cast<const bf16x8*>(kb);
        bf16x8 kf1 = *reinterpret_cast<const bf16x8*>(kb + 32);
        f32x4 a0 = __builtin_amdgcn_mfma_f32_16x16x32_bf16(qf[0][0], kf0, z, 0, 0, 0);
        S0[nt]   = __builtin_amdgcn_mfma_f32_16x16x32_bf16(qf[0][1], kf1, a0, 0, 0, 0);
        f32x4 a1 = __builtin_amdgcn_mfma_f32_16x16x32_bf16(qf[1][0], kf0, z, 0, 0, 0);
        S1[nt]   = __builtin_amdgcn_mfma_f32_16x16x32_bf16(qf[1][1], kf1, a1, 0, 0, 0);
    }

    // ---- softmax per tile; P (already / l) to wave-private LDS ----
#pragma unroll
    for (int t = 0; t < 2; ++t) {
        f32x4* S = t ? S1 : S0;
        float mrow[4] = {-1e30f, -1e30f, -1e30f, -1e30f};
#pragma unroll
        for (int nt = 0; nt < 10; ++nt)
#pragma unroll
            for (int r = 0; r < 4; ++r) {
                S[nt][r] *= 0.125f;
                mrow[r] = fmaxf(mrow[r], S[nt][r]);
            }
#pragma unroll
        for (int r = 0; r < 4; ++r) {
            mrow[r] = fmaxf(mrow[r], __shfl_xor(mrow[r], 1));
            mrow[r] = fmaxf(mrow[r], __shfl_xor(mrow[r], 2));
            mrow[r] = fmaxf(mrow[r], __shfl_xor(mrow[r], 4));
            mrow[r] = fmaxf(mrow[r], __shfl_xor(mrow[r], 8));
        }
        float lsum[4] = {0.f, 0.f, 0.f, 0.f};
#pragma unroll
        for (int nt = 0; nt < 10; ++nt)
#pragma unroll
            for (int r = 0; r < 4; ++r) {
                float e = __expf(S[nt][r] - mrow[r]);
                S[nt][r] = e;
                lsum[r] += e;
            }
#pragma unroll
        for (int r = 0; r < 4; ++r) {
            lsum[r] += __shfl_xor(lsum[r], 1);
            lsum[r] += __shfl_xor(lsum[r], 2);
            lsum[r] += __shfl_xor(lsum[r], 4);
            lsum[r] += __shfl_xor(lsum[r], 8);
            lsum[r] = 1.f / lsum[r];
        }
#pragma unroll
        for (int nt = 0; nt < 10; ++nt)
#pragma unroll
            for (int r = 0; r < 4; ++r)
                Pb[wave][(t * 16 + quad * 4 + r) * VT_STRIDE + nt * 16 + l16] =
                    f2bf(S[nt][r] * lsum[r]);
    }
    asm volatile("s_waitcnt lgkmcnt(0)" ::: "memory");   // wave-local P write->read

    // ---- O^T = Vt . P^T ; write into q-slot ----
#pragma unroll
    for (int dt = 0; dt < 4; ++dt) {
        f32x4 o0 = {0.f, 0.f, 0.f, 0.f}, o1 = {0.f, 0.f, 0.f, 0.f};
#pragma unroll
        for (int ks = 0; ks < 5; ++ks) {
            bf16x8 vf = *reinterpret_cast<const bf16x8*>(
                &Vt[(dt * 16 + l16) * VT_STRIDE + ks * 32 + quad * 8]);
            bf16x8 p0 = *reinterpret_cast<const bf16x8*>(
                &Pb[wave][(l16) * VT_STRIDE + ks * 32 + quad * 8]);
            bf16x8 p1 = *reinterpret_cast<const bf16x8*>(
                &Pb[wave][(16 + l16) * VT_STRIDE + ks * 32 + quad * 8]);
            o0 = __builtin_amdgcn_mfma_f32_16x16x32_bf16(vf, p0, o0, 0, 0, 0);
            o1 = __builtin_amdgcn_mfma_f32_16x16x32_bf16(vf, p1, o1, 0, 0, 0);
        }
#pragma unroll
        for (int t = 0; t < 2; ++t) {
            f32x4 o = t ? o1 : o0;
            ushort_t pk[4];
#pragma unroll
            for (int r = 0; r < 4; ++r) pk[r] = f2bf(o[r]);
            ushort_t* dst = basew + (size_t)(q0 + t * 16 + l16) * (3 * DD) +
                            dt * 16 + quad * 4;
            *(uint2*)dst = *(const uint2*)pk;
        }
    }
}

// ---------------------------------------------------------------------------
// 5) mask + grid aggregation + temporal mean.
//    Restructured: block per (chunk-of-49-hw, g, b); stage the 20 feat rows
//    (61 KB) + box bounds in LDS ONCE, then loop the 49 hw positions locally.
//    Old version re-read the same 20 rows from global 196x per (b,g)
//    (~94 MB effective traffic); now ~31 MB staged + LDS-local accumulate.
// ---------------------------------------------------------------------------
__global__ __launch_bounds__(256)
void mask_grid(const float* __restrict__ box, const float* __restrict__ feats,
               float* __restrict__ out)
{
    const int chunk = blockIdx.x;          // 0..3 (49 hw positions each)
    const int g = blockIdx.y;
    const int b = blockIdx.z;
    const int tid = threadIdx.x;

    __shared__ float fs[20][DD];           // 61,440 B
    __shared__ float x1s[20], x2s[20], y1s[20], y2s[20];

#pragma unroll 4
    for (int p = 0; p < 20; ++p) {
        int r = (b * TT + g * 2 + p / OO) * OO + (p % OO);
        const float* f = feats + (size_t)r * DD;
        fs[p][tid]       = f[tid];
        fs[p][tid + 256] = f[tid + 256];
        fs[p][tid + 512] = f[tid + 512];
    }
    if (tid < 20) {
        int t = g * 2 + tid / OO, o = tid % OO;
        const float* bx = box + (size_t)((b * TT + t) * OO + o) * 4;
        x1s[tid] = fminf(bx[0], bx[2]); x2s[tid] = fmaxf(bx[0], bx[2]);
        y1s[tid] = fminf(bx[1], bx[3]); y2s[tid] = fmaxf(bx[1], bx[3]);
    }
    __syncthreads();

    for (int q = 0; q < 49; ++q) {
        const int hw = chunk * 49 + q;
        const int hh = hw / GW, w = hw % GW;
        const float cy = (hh + 0.5f) / (float)GH;
        const float cx = (w  + 0.5f) / (float)GW;
        float a0 = 0.f, a1 = 0.f, a2 = 0.f;
#pragma unroll
        for (int p = 0; p < 20; ++p) {
            if (cy >= y1s[p] && cy <= y2s[p] && cx >= x1s[p] && cx <= x2s[p]) {
                a0 += fs[p][tid]; a1 += fs[p][tid + 256]; a2 += fs[p][tid + 512];
            }
        }
        float* op = out + ((size_t)b * (TGRP * GH * GW) + g * (GH * GW) + hw) * DD;
        op[tid]       = a0 * 0.5f;
        op[tid + 256] = a1 * 0.5f;
        op[tid + 512] = a2 * 0.5f;
    }
}

// ---------------------------------------------------------------------------
extern "C" void kernel_launch(void* const* d_in, const int* in_sizes, int n_in,
                              void* d_out, int out_size, void* d_ws, size_t ws_size,
                              hipStream_t stream)
{
    const float* box  = (const float*)d_in[0];
    const float* cat  = (const float*)d_in[1];
    const float* w1   = (const float*)d_in[2];
    const float* w2   = (const float*)d_in[3];
    const float* ln1g = (const float*)d_in[4];
    const float* ln1b = (const float*)d_in[5];
    const float* wqkv = (const float*)d_in[6];
    const float* wo   = (const float*)d_in[7];
    const float* bo   = (const float*)d_in[8];
    const float* ln2g = (const float*)d_in[9];
    const float* ln2b = (const float*)d_in[10];
    const float* wfc1 = (const float*)d_in[11];
    const float* bfc1 = (const float*)d_in[12];
    const float* wfc2 = (const float*)d_in[13];
    const float* bfc2 = (const float*)d_in[14];
    float* out = (float*)d_out;

    // workspace layout (byte offsets, 16B aligned), total 44,236,800 B.
    // [28,311,552 .. 44,236,800) is a "dead zone" at fc2 time: it hosts
    // transient buffers (hnb/wqkvT/woT/wfc1T/w2T/h, all dead before fc2) and
    // is re-used for the 2 x 7,864,320 B fc2 split-K fp32 partials.
    char* wsb = (char*)d_ws;
    float*    x     = (float*)   (wsb + 0);           //  7,864,320 (2560x768 f32)
    ushort_t* qkvb  = (ushort_t*)(wsb + 7864320);     // 15,728,640 (qkv 2560x2304 / fc1 2560x3072 overlay)
    ushort_t* fc1b  = qkvb;
    ushort_t* wfc2T = (ushort_t*)(wsb + 23592960);    //  4,718,592 (768x3072) live at fc2
    ushort_t* hnb   = (ushort_t*)(wsb + 28311552);    //  3,932,160 (2560x768)
    ushort_t* wqkvT = (ushort_t*)(wsb + 32243712);    //  3,538,944 (2304x768)
    ushort_t* woT   = (ushort_t*)(wsb + 35782656);    //  1,179,648 (768x768)
    ushort_t* wfc1T = (ushort_t*)(wsb + 36962304);    //  4,718,592 (3072x768)
    ushort_t* w2T   = (ushort_t*)(wsb + 41680896);    //    589,824 (768x384)
    ushort_t* h     = (ushort_t*)(wsb + 42270720);    //  1,966,080 (2560x384)
    float*    fc2P  = (float*)   (wsb + 28311552);    // 15,728,640 partials (overlays dead zone)

    transpose_w<<<dim3(2304 / 32, 768 / 32), 256, 0, stream>>>(wqkv, wqkvT, 768, 2304);
    transpose_w<<<dim3(768 / 32, 768 / 32), 256, 0, stream>>>(wo, woT, 768, 768);
    transpose_w<<<dim3(3072 / 32, 768 / 32), 256, 0, stream>>>(wfc1, wfc1T, 768, 3072);
    transpose_w<<<dim3(768 / 32, 3072 / 32), 256, 0, stream>>>(wfc2, wfc2T, 3072, 768);
    transpose_w<<<dim3(768 / 32, 384 / 32), 256, 0, stream>>>(w2, w2T, 384, 768);

    box_h<<<BL * 384 / 256, 256, 0, stream>>>(box, w1, h);
    // x = relu(h @ w2) + cat[t,o]   (32x32 tiles, 1920 waves)
    gemm_rf2<2, 2, 4, 1><<<dim3(24, 80, 1), 64, 0, stream>>>(
        h, 384, w2T, 384, nullptr, cat, x, nullptr, DD, 384);
    ln_kernel<<<BL, 256, 0, stream>>>(x, ln1g, ln1b, hnb);
    // qkv = hn @ wqkv   (32x64 tiles, 2880 waves = 2.8/SIMD)
    gemm_rf2<2, 4, 3, 1><<<dim3(36, 80, 1), 64, 0, stream>>>(
        hnb, DD, wqkvT, DD, nullptr, nullptr, nullptr, qkvb, 3 * DD, DD);
    attention_mfma<<<BATCH * NH, 320, 0, stream>>>(qkvb);
    // x += attn_out @ wo + bo   (32x32 tiles, 1920 waves, single writer)
    gemm_rf2<2, 2, 1, 1><<<dim3(24, 80, 1), 64, 0, stream>>>(
        qkvb, 3 * DD, woT, DD, bo, nullptr, x, nullptr, DD, DD);
    ln_kernel<<<BL, 256, 0, stream>>>(x, ln2g, ln2b, hnb);
    // fc1 = gelu(hn @ wfc1 + bfc1)   (32x64 tiles, 3840 waves = 3.75/SIMD)
    gemm_rf2<2, 4, 2, 1><<<dim3(48, 80, 1), 64, 0, stream>>>(
        hnb, DD, wfc1T, DD, bfc1, nullptr, nullptr, fc1b, 4 * DD, DD);
    // fc2 partials   (32x32 tiles, split2, 3840 waves = 3.75/SIMD, no atomics)
    gemm_rf2<2, 2, 5, 2><<<dim3(24, 80, 2), 64, 0, stream>>>(
        fc1b, 4 * DD, wfc2T, 4 * DD, nullptr, nullptr, fc2P, nullptr, DD, 4 * DD);
    // x += P0 + P1 + bfc2   (streaming reduce)
    reduce_fc2<<<BL * DD / 4 / 256, 256, 0, stream>>>(fc2P, bfc2, x);
    mask_grid<<<dim3(4, TGRP, BATCH), 256, 0, stream>>>(box, x, out);
}

// Round 7
// 361.269 us; speedup vs baseline: 1.2700x; 1.2700x over previous
//
#include <hip/hip_runtime.h>
#include <hip/hip_bf16.h>
#include <math.h>

// B=16, T=16, O=10, L=160, d=768, heads=12, dh=64, H=W=14, Tr=2.
// Out: (16, 8*196, 768) fp32.

#define BATCH 16
#define TT    16
#define OO    10
#define LL    160
#define BL    2560
#define DD    768
#define NH    12
#define DH    64
#define GH    14
#define GW    14
#define TGRP  8

typedef unsigned short ushort_t;
typedef __attribute__((ext_vector_type(8))) __bf16 bf16x8;
typedef __attribute__((ext_vector_type(4))) float f32x4;

__device__ __forceinline__ ushort_t f2bf(float f) {
    unsigned int u = __float_as_uint(f);
    u += 0x7fffu + ((u >> 16) & 1u);         // RNE
    return (ushort_t)(u >> 16);
}

// XCD chunk swizzle (T1): nwg % 8 == 0 for every launch using this.
__device__ __forceinline__ int swz_xcd(int bid, int nwg) {
    return (bid & 7) * (nwg >> 3) + (bid >> 3);
}

// ---------------------------------------------------------------------------
// 0) unified prep: 5 weight transposes (fp32 [K][N] -> bf16 [N][K]) + box_h,
//    all independent -> ONE wide dispatch instead of 6 serial small ones.
//    task ranges: wqkv 1728 | wo 576 | wfc1 2304 | wfc2 2304 | w2 288 | box_h 3840
// ---------------------------------------------------------------------------
__global__ __launch_bounds__(256)
void prep_all(const float* __restrict__ wqkv, const float* __restrict__ wo,
              const float* __restrict__ wfc1, const float* __restrict__ wfc2,
              const float* __restrict__ w2, const float* __restrict__ box,
              const float* __restrict__ w1,
              ushort_t* __restrict__ wqkvT, ushort_t* __restrict__ woT,
              ushort_t* __restrict__ wfc1T, ushort_t* __restrict__ wfc2T,
              ushort_t* __restrict__ w2T, ushort_t* __restrict__ h)
{
    __shared__ float s[32][33];
    int t = blockIdx.x;
    const float* W; ushort_t* Wt; int K, N, nx;
    if (t < 1728)      {            W = wqkv; Wt = wqkvT; K = 768;  N = 2304; nx = 72; }
    else if (t < 2304) { t -= 1728; W = wo;   Wt = woT;   K = 768;  N = 768;  nx = 24; }
    else if (t < 4608) { t -= 2304; W = wfc1; Wt = wfc1T; K = 768;  N = 3072; nx = 96; }
    else if (t < 6912) { t -= 4608; W = wfc2; Wt = wfc2T; K = 3072; N = 768;  nx = 24; }
    else if (t < 7200) { t -= 6912; W = w2;   Wt = w2T;   K = 384;  N = 768;  nx = 24; }
    else {
        // box_h: h = relu(box @ w1) -> bf16 [2560][384]
        const int i2 = (t - 7200) * 256 + threadIdx.x;      // 0..983039
        const int r = i2 / 384, j = i2 - r * 384;
        const float* bx = box + (size_t)r * 4;
        float v = bx[0] * w1[j] + bx[1] * w1[384 + j] +
                  bx[2] * w1[768 + j] + bx[3] * w1[1152 + j];
        h[i2] = f2bf(fmaxf(v, 0.f));
        return;
    }
    const int n0 = (t % nx) * 32, k0 = (t / nx) * 32;
    const int tx = threadIdx.x & 31, ty = threadIdx.x >> 5;   // ty 0..7
#pragma unroll
    for (int r = 0; r < 4; ++r)
        s[ty + r * 8][tx] = W[(size_t)(k0 + ty + r * 8) * N + n0 + tx];
    __syncthreads();
#pragma unroll
    for (int r = 0; r < 4; ++r)
        Wt[(size_t)(n0 + ty + r * 8) * K + k0 + tx] = f2bf(s[tx][ty + r * 8]);
}

// ---------------------------------------------------------------------------
// 2) LayerNorm -> bf16 output
// ---------------------------------------------------------------------------
__global__ __launch_bounds__(256)
void ln_kernel(const float* __restrict__ in, const float* __restrict__ g,
               const float* __restrict__ bvec, ushort_t* __restrict__ out)
{
    const int r = blockIdx.x;
    const int tid = threadIdx.x;
    const float* row = in + (size_t)r * DD;
    float v0 = row[tid], v1 = row[tid + 256], v2 = row[tid + 512];
    float s  = v0 + v1 + v2;
    float s2 = v0 * v0 + v1 * v1 + v2 * v2;
#pragma unroll
    for (int off = 32; off > 0; off >>= 1) {
        s  += __shfl_down(s, off);
        s2 += __shfl_down(s2, off);
    }
    __shared__ float red[8];
    int wave = tid >> 6, lane = tid & 63;
    if (lane == 0) { red[wave] = s; red[wave + 4] = s2; }
    __syncthreads();
    s  = red[0] + red[1] + red[2] + red[3];
    s2 = red[4] + red[5] + red[6] + red[7];
    float mu  = s * (1.f / DD);
    float var = s2 * (1.f / DD) - mu * mu;
    float inv = rsqrtf(var + 1e-5f);
    ushort_t* op = out + (size_t)r * DD;
    op[tid]       = f2bf((v0 - mu) * inv * g[tid]       + bvec[tid]);
    op[tid + 256] = f2bf((v1 - mu) * inv * g[tid + 256] + bvec[tid + 256]);
    op[tid + 512] = f2bf((v2 - mu) * inv * g[tid + 512] + bvec[tid + 512]);
}

// ---------------------------------------------------------------------------
// 3a) register-fragment bf16 MFMA GEMM (64x64, 1 wave/block), for xproj only.
//     MODE 4: Cf = relu(acc) + cat[(row%160)][col]
// ---------------------------------------------------------------------------
template <int MI, int NJ, int MODE, int SPLIT>
__global__ __launch_bounds__(64)
void gemm_rf2(const ushort_t* __restrict__ A, int lda,
              const ushort_t* __restrict__ Bt, int ldb,
              const float* __restrict__ bias, const float* __restrict__ cat,
              float* __restrict__ Cf, ushort_t* __restrict__ Cb,
              int ldc, int K)
{
    const int lane = threadIdx.x;
    const int l16 = lane & 15, quad = lane >> 4;

    const int nwg = gridDim.x * gridDim.y * gridDim.z;
    const int bid = blockIdx.x + gridDim.x * (blockIdx.y + gridDim.y * blockIdx.z);
    const int w   = swz_xcd(bid, nwg);
    const int bx  = w % gridDim.x;
    const int byz = w / gridDim.x;
    const int by  = byz % gridDim.y;
    const int bz  = byz / gridDim.y;

    const int row0 = by * (MI * 16), col0 = bx * (NJ * 16);
    const int Kper = K / SPLIT;                 // multiple of 64
    const int k0   = bz * Kper;

    const ushort_t* ap = A  + (size_t)(row0 + l16) * lda + k0 + quad * 8;
    const ushort_t* bp = Bt + (size_t)(col0 + l16) * ldb + k0 + quad * 8;

    f32x4 acc[MI][NJ];
#pragma unroll
    for (int i = 0; i < MI; ++i)
#pragma unroll
        for (int j = 0; j < NJ; ++j) {
            acc[i][j][0] = 0.f; acc[i][j][1] = 0.f;
            acc[i][j][2] = 0.f; acc[i][j][3] = 0.f;
        }

#define LOADF2(aa, bb, kk)                                                       \
    _Pragma("unroll")                                                            \
    for (int i = 0; i < MI; ++i)                                                 \
        aa[i] = *reinterpret_cast<const bf16x8*>(ap + (size_t)(i * 16) * lda + (kk)); \
    _Pragma("unroll")                                                            \
    for (int j = 0; j < NJ; ++j)                                                 \
        bb[j] = *reinterpret_cast<const bf16x8*>(bp + (size_t)(j * 16) * ldb + (kk));
#define MFMA2(aa, bb)                                                            \
    _Pragma("unroll")                                                            \
    for (int i = 0; i < MI; ++i)                                                 \
        _Pragma("unroll")                                                        \
        for (int j = 0; j < NJ; ++j)                                             \
            acc[i][j] = __builtin_amdgcn_mfma_f32_16x16x32_bf16(aa[i], bb[j], acc[i][j], 0, 0, 0);

    bf16x8 a0[MI], b0[NJ], a1[MI], b1[NJ];
    LOADF2(a0, b0, 0)
    int kt = 0;
    for (; kt + 64 < Kper; kt += 64) {
        LOADF2(a1, b1, kt + 32)
        MFMA2(a0, b0)
        LOADF2(a0, b0, kt + 64)
        MFMA2(a1, b1)
    }
    LOADF2(a1, b1, kt + 32)
    MFMA2(a0, b0)
    MFMA2(a1, b1)
#undef LOADF2
#undef MFMA2

    // epilogue: C/D layout col=lane&15, row=(lane>>4)*4+reg (HW-verified)
    const int q4 = quad * 4;
#pragma unroll
    for (int i = 0; i < MI; ++i)
#pragma unroll
        for (int j = 0; j < NJ; ++j) {
            const int gcol = col0 + j * 16 + l16;
            const float bj = (MODE == 1 || MODE == 2) ? bias[gcol] : 0.f;
#pragma unroll
            for (int r = 0; r < 4; ++r) {
                const int grow = row0 + i * 16 + q4 + r;
                const size_t idx = (size_t)grow * ldc + gcol;
                const float v = acc[i][j][r];
                if (MODE == 1) {
                    Cf[idx] += v + bj;
                } else if (MODE == 2) {
                    const float u = v + bj;
                    Cb[idx] = f2bf(0.5f * u * (1.f + erff(u * 0.70710678118654752f)));
                } else if (MODE == 3) {
                    Cb[idx] = f2bf(v);
                } else {
                    Cf[idx] = fmaxf(v, 0.f) + cat[(size_t)(grow % LL) * DD + gcol];
                }
            }
        }
}

// ---------------------------------------------------------------------------
// 3b) LDS-staged bf16 MFMA GEMM (R3-proven, measured-best): 128x128 tile,
//     4 waves, BK=64, double-buffered global_load_lds, one __syncthreads per
//     step, k8-chunk-major LDS (0 bank conflicts), XCD chunk-swizzle.
//     MODE 1: Cf += acc + bias (atomicAdd when SPLIT>1; bias only slice 0)
//     MODE 2: Cb = bf16(gelu(acc+bias))
//     MODE 3: Cb = bf16(acc)
// ---------------------------------------------------------------------------
#define GLL(gp, lp) __builtin_amdgcn_global_load_lds(                       \
    (const __attribute__((address_space(1))) void*)(gp),                     \
    (__attribute__((address_space(3))) void*)(lp), 16, 0, 0)

template <int MODE, int SPLIT>
__global__ __launch_bounds__(256)
void gemm_lds(const ushort_t* __restrict__ A, int lda,
              const ushort_t* __restrict__ Bt, int ldb,
              const float* __restrict__ bias,
              float* __restrict__ Cf, ushort_t* __restrict__ Cb,
              int ldc, int K)
{
    __shared__ ushort_t As[2][8192];   // [buf][k8*128*8 + row*8 + e], 128 x 64
    __shared__ ushort_t Bs[2][8192];

    const int t    = threadIdx.x;          // 0..255
    const int wv   = t >> 6;               // wave 0..3 (uniform per wave)
    const int lane = t & 63;
    const int l16  = lane & 15, quad = lane >> 4;
    const int wr   = (wv >> 1) * 64;       // wave's 64x64 quadrant
    const int wc   = (wv & 1) * 64;

    // XCD-swizzled block id
    const int nwg = gridDim.x * gridDim.y * gridDim.z;
    const int bid = blockIdx.x + gridDim.x * (blockIdx.y + gridDim.y * blockIdx.z);
    const int w   = swz_xcd(bid, nwg);
    const int bx  = w % gridDim.x;
    const int byz = w / gridDim.x;
    const int by  = byz % gridDim.y;
    const int bz  = byz / gridDim.y;

    const int row0 = by * 128, col0 = bx * 128;
    const int Kper = K / SPLIT;
    const int k0   = bz * Kper;
    const int steps = Kper / 64;

    const ushort_t* Ag = A  + (size_t)(row0 + (t & 127)) * lda + k0 + ((t >> 7) * 8);
    const ushort_t* Bg = Bt + (size_t)(col0 + (t & 127)) * ldb + k0 + ((t >> 7) * 8);

#define STAGE(c, kk) do {                                                    \
        _Pragma("unroll")                                                    \
        for (int ii = 0; ii < 4; ++ii) {                                     \
            GLL(Ag + (kk) + ii * 16, &As[c][ii * 2048 + wv * 512]);          \
            GLL(Bg + (kk) + ii * 16, &Bs[c][ii * 2048 + wv * 512]);          \
        }                                                                    \
    } while (0)

    f32x4 acc[4][4];
#pragma unroll
    for (int i = 0; i < 4; ++i)
#pragma unroll
        for (int j = 0; j < 4; ++j) {
            acc[i][j][0] = 0.f; acc[i][j][1] = 0.f;
            acc[i][j][2] = 0.f; acc[i][j][3] = 0.f;
        }

    STAGE(0, 0);
    __syncthreads();                       // drains vmcnt(0): buf0 ready
    int cur = 0;
    for (int s = 0; s < steps; ++s) {
        if (s + 1 < steps) STAGE(cur ^ 1, (s + 1) * 64);   // async prefetch
#pragma unroll
        for (int ks = 0; ks < 2; ++ks) {
            bf16x8 af[4], bfr[4];
#pragma unroll
            for (int i = 0; i < 4; ++i)
                af[i] = *reinterpret_cast<const bf16x8*>(
                    &As[cur][((ks * 4 + quad) * 128 + wr + i * 16 + l16) * 8]);
#pragma unroll
            for (int j = 0; j < 4; ++j)
                bfr[j] = *reinterpret_cast<const bf16x8*>(
                    &Bs[cur][((ks * 4 + quad) * 128 + wc + j * 16 + l16) * 8]);
#pragma unroll
            for (int i = 0; i < 4; ++i)
#pragma unroll
                for (int j = 0; j < 4; ++j)
                    acc[i][j] = __builtin_amdgcn_mfma_f32_16x16x32_bf16(
                        af[i], bfr[j], acc[i][j], 0, 0, 0);
        }
        __syncthreads();                   // drains prefetch + guards buf reuse
        cur ^= 1;
    }
#undef STAGE

    // epilogue: C/D layout col=lane&15, row=(lane>>4)*4+reg
    const int q4 = quad * 4;
    const int r0w = row0 + wr, c0w = col0 + wc;
#pragma unroll
    for (int i = 0; i < 4; ++i)
#pragma unroll
        for (int j = 0; j < 4; ++j) {
            const int gcol = c0w + j * 16 + l16;
            const float bj = (MODE == 1 || MODE == 2)
                               ? ((SPLIT == 1 || bz == 0) ? bias[gcol] : 0.f)
                               : 0.f;
#pragma unroll
            for (int r = 0; r < 4; ++r) {
                const int grow = r0w + i * 16 + q4 + r;
                const size_t idx = (size_t)grow * ldc + gcol;
                const float v = acc[i][j][r];
                if (MODE == 1) {
                    if (SPLIT > 1) atomicAdd(&Cf[idx], v + bj);
                    else           Cf[idx] += v + bj;
                } else if (MODE == 2) {
                    const float u = v + bj;
                    Cb[idx] = f2bf(0.5f * u * (1.f + erff(u * 0.70710678118654752f)));
                } else {
                    Cb[idx] = f2bf(v);
                }
            }
        }
}

// ---------------------------------------------------------------------------
// 4) MFMA attention, q-split: block per (half, b*NH+h), 5 waves; each wave
//    handles ONE 16-row q-tile (q0 = half*80 + wave*16).  384 blocks
//    (1.5/CU vs 0.75 before), LDS 71 KB -> 2 blocks/CU co-resident.
//    Output written back into the (dead) q-slot of qkv.
// ---------------------------------------------------------------------------
#define KS_STRIDE 72
#define VT_STRIDE 168
__global__ __launch_bounds__(320)
void attention_mfma(ushort_t* __restrict__ qkv)
{
    __shared__ ushort_t Ks[160 * KS_STRIDE];
    __shared__ ushort_t Vt[64 * VT_STRIDE];
    __shared__ ushort_t Pb[5][16 * VT_STRIDE];

    const int half = blockIdx.x;          // 0..1
    const int b  = blockIdx.y / NH;
    const int hh = blockIdx.y % NH;
    ushort_t* basew = qkv + (size_t)b * LL * (3 * DD) + hh * DH;
    const ushort_t* base = basew;
    const int tid  = threadIdx.x;
    const int wave = tid >> 6, lane = tid & 63;
    const int l16 = lane & 15, quad = lane >> 4;

    // ---- stage K rows and V transposed (all 160 kv rows) ----
#pragma unroll
    for (int it = 0; it < 4; ++it) {
        int idx = tid + it * 320;                 // 0..1279
        int l = idx >> 3, c8 = (idx & 7) * 8;
        uint4 kv = *(const uint4*)(base + (size_t)l * (3 * DD) + DD + c8);
        *(uint4*)&Ks[l * KS_STRIDE + c8] = kv;
        uint4 vv = *(const uint4*)(base + (size_t)l * (3 * DD) + 2 * DD + c8);
        ushort_t e[8];
        *(uint4*)e = vv;
#pragma unroll
        for (int i = 0; i < 8; ++i)
            Vt[(c8 + i) * VT_STRIDE + l] = e[i];
    }

    // ---- Q fragments straight from global (one 16-row tile per wave) ----
    const int q0 = half * 80 + wave * 16;
    bf16x8 qf[2];
#pragma unroll
    for (int k = 0; k < 2; ++k)
        qf[k] = *reinterpret_cast<const bf16x8*>(
            base + (size_t)(q0 + l16) * (3 * DD) + k * 32 + quad * 8);

    __syncthreads();

    // ---- S = QK^T ----
    f32x4 S[10];
#pragma unroll
    for (int nt = 0; nt < 10; ++nt) {
        f32x4 z = {0.f, 0.f, 0.f, 0.f};
        const ushort_t* kb = &Ks[(nt * 16 + l16) * KS_STRIDE + quad * 8];
        bf16x8 kf0 = *reinterpret_cast<const bf16x8*>(kb);
        bf16x8 kf1 = *reinterpret_cast<const bf16x8*>(kb + 32);
        f32x4 a0 = __builtin_amdgcn_mfma_f32_16x16x32_bf16(qf[0], kf0, z, 0, 0, 0);
        S[nt]    = __builtin_amdgcn_mfma_f32_16x16x32_bf16(qf[1], kf1, a0, 0, 0, 0);
    }

    // ---- softmax; P (already / l) to wave-private LDS ----
    {
        float mrow[4] = {-1e30f, -1e30f, -1e30f, -1e30f};
#pragma unroll
        for (int nt = 0; nt < 10; ++nt)
#pragma unroll
            for (int r = 0; r < 4; ++r) {
                S[nt][r] *= 0.125f;
                mrow[r] = fmaxf(mrow[r], S[nt][r]);
            }
#pragma unroll
        for (int r = 0; r < 4; ++r) {
            mrow[r] = fmaxf(mrow[r], __shfl_xor(mrow[r], 1));
            mrow[r] = fmaxf(mrow[r], __shfl_xor(mrow[r], 2));
            mrow[r] = fmaxf(mrow[r], __shfl_xor(mrow[r], 4));
            mrow[r] = fmaxf(mrow[r], __shfl_xor(mrow[r], 8));
        }
        float lsum[4] = {0.f, 0.f, 0.f, 0.f};
#pragma unroll
        for (int nt = 0; nt < 10; ++nt)
#pragma unroll
            for (int r = 0; r < 4; ++r) {
                float e = __expf(S[nt][r] - mrow[r]);
                S[nt][r] = e;
                lsum[r] += e;
            }
#pragma unroll
        for (int r = 0; r < 4; ++r) {
            lsum[r] += __shfl_xor(lsum[r], 1);
            lsum[r] += __shfl_xor(lsum[r], 2);
            lsum[r] += __shfl_xor(lsum[r], 4);
            lsum[r] += __shfl_xor(lsum[r], 8);
            lsum[r] = 1.f / lsum[r];
        }
#pragma unroll
        for (int nt = 0; nt < 10; ++nt)
#pragma unroll
            for (int r = 0; r < 4; ++r)
                Pb[wave][(quad * 4 + r) * VT_STRIDE + nt * 16 + l16] =
                    f2bf(S[nt][r] * lsum[r]);
    }
    asm volatile("s_waitcnt lgkmcnt(0)" ::: "memory");   // wave-local P write->read

    // ---- O^T = Vt . P^T ; write into q-slot ----
#pragma unroll
    for (int dt = 0; dt < 4; ++dt) {
        f32x4 o0 = {0.f, 0.f, 0.f, 0.f};
#pragma unroll
        for (int ks = 0; ks < 5; ++ks) {
            bf16x8 vf = *reinterpret_cast<const bf16x8*>(
                &Vt[(dt * 16 + l16) * VT_STRIDE + ks * 32 + quad * 8]);
            bf16x8 p0 = *reinterpret_cast<const bf16x8*>(
                &Pb[wave][(l16) * VT_STRIDE + ks * 32 + quad * 8]);
            o0 = __builtin_amdgcn_mfma_f32_16x16x32_bf16(vf, p0, o0, 0, 0, 0);
        }
        ushort_t pk[4];
#pragma unroll
        for (int r = 0; r < 4; ++r) pk[r] = f2bf(o0[r]);
        ushort_t* dst = basew + (size_t)(q0 + l16) * (3 * DD) + dt * 16 + quad * 4;
        *(uint2*)dst = *(const uint2*)pk;
    }
}

// ---------------------------------------------------------------------------
// 5) mask + grid aggregation + temporal mean (LDS-staged, validated in R6)
// ---------------------------------------------------------------------------
__global__ __launch_bounds__(256)
void mask_grid(const float* __restrict__ box, const float* __restrict__ feats,
               float* __restrict__ out)
{
    const int chunk = blockIdx.x;          // 0..3 (49 hw positions each)
    const int g = blockIdx.y;
    const int b = blockIdx.z;
    const int tid = threadIdx.x;

    __shared__ float fs[20][DD];           // 61,440 B
    __shared__ float x1s[20], x2s[20], y1s[20], y2s[20];

#pragma unroll 4
    for (int p = 0; p < 20; ++p) {
        int r = (b * TT + g * 2 + p / OO) * OO + (p % OO);
        const float* f = feats + (size_t)r * DD;
        fs[p][tid]       = f[tid];
        fs[p][tid + 256] = f[tid + 256];
        fs[p][tid + 512] = f[tid + 512];
    }
    if (tid < 20) {
        int t = g * 2 + tid / OO, o = tid % OO;
        const float* bx = box + (size_t)((b * TT + t) * OO + o) * 4;
        x1s[tid] = fminf(bx[0], bx[2]); x2s[tid] = fmaxf(bx[0], bx[2]);
        y1s[tid] = fminf(bx[1], bx[3]); y2s[tid] = fmaxf(bx[1], bx[3]);
    }
    __syncthreads();

    for (int q = 0; q < 49; ++q) {
        const int hw = chunk * 49 + q;
        const int hh = hw / GW, w = hw % GW;
        const float cy = (hh + 0.5f) / (float)GH;
        const float cx = (w  + 0.5f) / (float)GW;
        float a0 = 0.f, a1 = 0.f, a2 = 0.f;
#pragma unroll
        for (int p = 0; p < 20; ++p) {
            if (cy >= y1s[p] && cy <= y2s[p] && cx >= x1s[p] && cx <= x2s[p]) {
                a0 += fs[p][tid]; a1 += fs[p][tid + 256]; a2 += fs[p][tid + 512];
            }
        }
        float* op = out + ((size_t)b * (TGRP * GH * GW) + g * (GH * GW) + hw) * DD;
        op[tid]       = a0 * 0.5f;
        op[tid + 256] = a1 * 0.5f;
        op[tid + 512] = a2 * 0.5f;
    }
}

// ---------------------------------------------------------------------------
extern "C" void kernel_launch(void* const* d_in, const int* in_sizes, int n_in,
                              void* d_out, int out_size, void* d_ws, size_t ws_size,
                              hipStream_t stream)
{
    const float* box  = (const float*)d_in[0];
    const float* cat  = (const float*)d_in[1];
    const float* w1   = (const float*)d_in[2];
    const float* w2   = (const float*)d_in[3];
    const float* ln1g = (const float*)d_in[4];
    const float* ln1b = (const float*)d_in[5];
    const float* wqkv = (const float*)d_in[6];
    const float* wo   = (const float*)d_in[7];
    const float* bo   = (const float*)d_in[8];
    const float* ln2g = (const float*)d_in[9];
    const float* ln2b = (const float*)d_in[10];
    const float* wfc1 = (const float*)d_in[11];
    const float* bfc1 = (const float*)d_in[12];
    const float* wfc2 = (const float*)d_in[13];
    const float* bfc2 = (const float*)d_in[14];
    float* out = (float*)d_out;

    // workspace layout (byte offsets, 16B aligned), total 44,236,800 B
    char* wsb = (char*)d_ws;
    float*    x     = (float*)   (wsb + 0);           //  7,864,320 (2560x768 f32)
    ushort_t* qkvb  = (ushort_t*)(wsb + 7864320);     // 15,728,640 (qkv 2560x2304 / fc1 2560x3072 overlay)
    ushort_t* fc1b  = qkvb;
    ushort_t* wfc2T = (ushort_t*)(wsb + 23592960);    //  4,718,592 (768x3072)
    ushort_t* hnb   = (ushort_t*)(wsb + 28311552);    //  3,932,160 (2560x768)
    ushort_t* wqkvT = (ushort_t*)(wsb + 32243712);    //  3,538,944 (2304x768)
    ushort_t* woT   = (ushort_t*)(wsb + 35782656);    //  1,179,648 (768x768)
    ushort_t* wfc1T = (ushort_t*)(wsb + 36962304);    //  4,718,592 (3072x768)
    ushort_t* w2T   = (ushort_t*)(wsb + 41680896);    //    589,824 (768x384)
    ushort_t* h     = (ushort_t*)(wsb + 42270720);    //  1,966,080 (2560x384)

    // all prep work (5 transposes + box_h) in ONE wide dispatch
    prep_all<<<11040, 256, 0, stream>>>(wqkv, wo, wfc1, wfc2, w2, box, w1,
                                        wqkvT, woT, wfc1T, wfc2T, w2T, h);
    // x = relu(h @ w2) + cat[t,o]   (64x64 rf, 480 1-wave blocks)
    gemm_rf2<4, 4, 4, 1><<<dim3(12, 40, 1), 64, 0, stream>>>(
        h, 384, w2T, 384, nullptr, cat, x, nullptr, DD, 384);
    ln_kernel<<<BL, 256, 0, stream>>>(x, ln1g, ln1b, hnb);
    // qkv = hn @ wqkv   (360 blocks, 12 steps)
    gemm_lds<3, 1><<<dim3(2304 / 128, 2560 / 128, 1), 256, 0, stream>>>(
        hnb, DD, wqkvT, DD, nullptr, nullptr, qkvb, 3 * DD, DD);
    // attention, q-split: 384 blocks
    attention_mfma<<<dim3(2, BATCH * NH), 320, 0, stream>>>(qkvb);
    // x += attn_out @ wo + bo   (split2, 240 blocks, 6 steps — R3 config)
    gemm_lds<1, 2><<<dim3(768 / 128, 2560 / 128, 2), 256, 0, stream>>>(
        qkvb, 3 * DD, woT, DD, bo, x, nullptr, DD, DD);
    ln_kernel<<<BL, 256, 0, stream>>>(x, ln2g, ln2b, hnb);
    // fc1 = gelu(hn @ wfc1 + bfc1)   (480 blocks, 12 steps)
    gemm_lds<2, 1><<<dim3(3072 / 128, 2560 / 128, 1), 256, 0, stream>>>(
        hnb, DD, wfc1T, DD, bfc1, nullptr, fc1b, 4 * DD, DD);
    // x += gelu_fc1 @ wfc2 + bfc2   (split4, 480 blocks, 12 steps — R3 config)
    gemm_lds<1, 4><<<dim3(768 / 128, 2560 / 128, 4), 256, 0, stream>>>(
        fc1b, 4 * DD, wfc2T, 4 * DD, bfc2, x, nullptr, DD, 4 * DD);
    mask_grid<<<dim3(4, TGRP, BATCH), 256, 0, stream>>>(box, x, out);
}

// Round 8
// 325.763 us; speedup vs baseline: 1.4084x; 1.1090x over previous
//
#include <hip/hip_runtime.h>
#include <hip/hip_bf16.h>
#include <math.h>

// B=16, T=16, O=10, L=160, d=768, heads=12, dh=64, H=W=14, Tr=2.
// Out: (16, 8*196, 768) fp32.

#define BATCH 16
#define TT    16
#define OO    10
#define LL    160
#define BL    2560
#define DD    768
#define NH    12
#define DH    64
#define GH    14
#define GW    14
#define TGRP  8

typedef unsigned short ushort_t;
typedef __attribute__((ext_vector_type(8))) __bf16 bf16x8;
typedef __attribute__((ext_vector_type(4))) float f32x4;

__device__ __forceinline__ ushort_t f2bf(float f) {
    unsigned int u = __float_as_uint(f);
    u += 0x7fffu + ((u >> 16) & 1u);         // RNE
    return (ushort_t)(u >> 16);
}

// XCD chunk swizzle (T1): nwg % 8 == 0 for every launch using this.
__device__ __forceinline__ int swz_xcd(int bid, int nwg) {
    return (bid & 7) * (nwg >> 3) + (bid >> 3);
}

// ---------------------------------------------------------------------------
// 0) unified prep: 5 weight transposes (fp32 [K][N] -> bf16 [N][K]) + box_h,
//    all independent -> ONE wide dispatch instead of 6 serial small ones.
//    task ranges: wqkv 1728 | wo 576 | wfc1 2304 | wfc2 2304 | w2 288 | box_h 3840
// ---------------------------------------------------------------------------
__global__ __launch_bounds__(256)
void prep_all(const float* __restrict__ wqkv, const float* __restrict__ wo,
              const float* __restrict__ wfc1, const float* __restrict__ wfc2,
              const float* __restrict__ w2, const float* __restrict__ box,
              const float* __restrict__ w1,
              ushort_t* __restrict__ wqkvT, ushort_t* __restrict__ woT,
              ushort_t* __restrict__ wfc1T, ushort_t* __restrict__ wfc2T,
              ushort_t* __restrict__ w2T, ushort_t* __restrict__ h)
{
    __shared__ float s[32][33];
    int t = blockIdx.x;
    const float* W; ushort_t* Wt; int K, N, nx;
    if (t < 1728)      {            W = wqkv; Wt = wqkvT; K = 768;  N = 2304; nx = 72; }
    else if (t < 2304) { t -= 1728; W = wo;   Wt = woT;   K = 768;  N = 768;  nx = 24; }
    else if (t < 4608) { t -= 2304; W = wfc1; Wt = wfc1T; K = 768;  N = 3072; nx = 96; }
    else if (t < 6912) { t -= 4608; W = wfc2; Wt = wfc2T; K = 3072; N = 768;  nx = 24; }
    else if (t < 7200) { t -= 6912; W = w2;   Wt = w2T;   K = 384;  N = 768;  nx = 24; }
    else {
        // box_h: h = relu(box @ w1) -> bf16 [2560][384]
        const int i2 = (t - 7200) * 256 + threadIdx.x;      // 0..983039
        const int r = i2 / 384, j = i2 - r * 384;
        const float* bx = box + (size_t)r * 4;
        float v = bx[0] * w1[j] + bx[1] * w1[384 + j] +
                  bx[2] * w1[768 + j] + bx[3] * w1[1152 + j];
        h[i2] = f2bf(fmaxf(v, 0.f));
        return;
    }
    const int n0 = (t % nx) * 32, k0 = (t / nx) * 32;
    const int tx = threadIdx.x & 31, ty = threadIdx.x >> 5;   // ty 0..7
#pragma unroll
    for (int r = 0; r < 4; ++r)
        s[ty + r * 8][tx] = W[(size_t)(k0 + ty + r * 8) * N + n0 + tx];
    __syncthreads();
#pragma unroll
    for (int r = 0; r < 4; ++r)
        Wt[(size_t)(n0 + ty + r * 8) * K + k0 + tx] = f2bf(s[tx][ty + r * 8]);
}

// ---------------------------------------------------------------------------
// 2) LayerNorm -> bf16 output
// ---------------------------------------------------------------------------
__global__ __launch_bounds__(256)
void ln_kernel(const float* __restrict__ in, const float* __restrict__ g,
               const float* __restrict__ bvec, ushort_t* __restrict__ out)
{
    const int r = blockIdx.x;
    const int tid = threadIdx.x;
    const float* row = in + (size_t)r * DD;
    float v0 = row[tid], v1 = row[tid + 256], v2 = row[tid + 512];
    float s  = v0 + v1 + v2;
    float s2 = v0 * v0 + v1 * v1 + v2 * v2;
#pragma unroll
    for (int off = 32; off > 0; off >>= 1) {
        s  += __shfl_down(s, off);
        s2 += __shfl_down(s2, off);
    }
    __shared__ float red[8];
    int wave = tid >> 6, lane = tid & 63;
    if (lane == 0) { red[wave] = s; red[wave + 4] = s2; }
    __syncthreads();
    s  = red[0] + red[1] + red[2] + red[3];
    s2 = red[4] + red[5] + red[6] + red[7];
    float mu  = s * (1.f / DD);
    float var = s2 * (1.f / DD) - mu * mu;
    float inv = rsqrtf(var + 1e-5f);
    ushort_t* op = out + (size_t)r * DD;
    op[tid]       = f2bf((v0 - mu) * inv * g[tid]       + bvec[tid]);
    op[tid + 256] = f2bf((v1 - mu) * inv * g[tid + 256] + bvec[tid + 256]);
    op[tid + 512] = f2bf((v2 - mu) * inv * g[tid + 512] + bvec[tid + 512]);
}

// ---------------------------------------------------------------------------
// 3a) register-fragment bf16 MFMA GEMM (64x64, 1 wave/block), for xproj only.
//     MODE 4: Cf = relu(acc) + cat[(row%160)][col]
// ---------------------------------------------------------------------------
template <int MI, int NJ, int MODE, int SPLIT>
__global__ __launch_bounds__(64)
void gemm_rf2(const ushort_t* __restrict__ A, int lda,
              const ushort_t* __restrict__ Bt, int ldb,
              const float* __restrict__ bias, const float* __restrict__ cat,
              float* __restrict__ Cf, ushort_t* __restrict__ Cb,
              int ldc, int K)
{
    const int lane = threadIdx.x;
    const int l16 = lane & 15, quad = lane >> 4;

    const int nwg = gridDim.x * gridDim.y * gridDim.z;
    const int bid = blockIdx.x + gridDim.x * (blockIdx.y + gridDim.y * blockIdx.z);
    const int w   = swz_xcd(bid, nwg);
    const int bx  = w % gridDim.x;
    const int byz = w / gridDim.x;
    const int by  = byz % gridDim.y;
    const int bz  = byz / gridDim.y;

    const int row0 = by * (MI * 16), col0 = bx * (NJ * 16);
    const int Kper = K / SPLIT;                 // multiple of 64
    const int k0   = bz * Kper;

    const ushort_t* ap = A  + (size_t)(row0 + l16) * lda + k0 + quad * 8;
    const ushort_t* bp = Bt + (size_t)(col0 + l16) * ldb + k0 + quad * 8;

    f32x4 acc[MI][NJ];
#pragma unroll
    for (int i = 0; i < MI; ++i)
#pragma unroll
        for (int j = 0; j < NJ; ++j) {
            acc[i][j][0] = 0.f; acc[i][j][1] = 0.f;
            acc[i][j][2] = 0.f; acc[i][j][3] = 0.f;
        }

#define LOADF2(aa, bb, kk)                                                       \
    _Pragma("unroll")                                                            \
    for (int i = 0; i < MI; ++i)                                                 \
        aa[i] = *reinterpret_cast<const bf16x8*>(ap + (size_t)(i * 16) * lda + (kk)); \
    _Pragma("unroll")                                                            \
    for (int j = 0; j < NJ; ++j)                                                 \
        bb[j] = *reinterpret_cast<const bf16x8*>(bp + (size_t)(j * 16) * ldb + (kk));
#define MFMA2(aa, bb)                                                            \
    _Pragma("unroll")                                                            \
    for (int i = 0; i < MI; ++i)                                                 \
        _Pragma("unroll")                                                        \
        for (int j = 0; j < NJ; ++j)                                             \
            acc[i][j] = __builtin_amdgcn_mfma_f32_16x16x32_bf16(aa[i], bb[j], acc[i][j], 0, 0, 0);

    bf16x8 a0[MI], b0[NJ], a1[MI], b1[NJ];
    LOADF2(a0, b0, 0)
    int kt = 0;
    for (; kt + 64 < Kper; kt += 64) {
        LOADF2(a1, b1, kt + 32)
        MFMA2(a0, b0)
        LOADF2(a0, b0, kt + 64)
        MFMA2(a1, b1)
    }
    LOADF2(a1, b1, kt + 32)
    MFMA2(a0, b0)
    MFMA2(a1, b1)
#undef LOADF2
#undef MFMA2

    // epilogue: C/D layout col=lane&15, row=(lane>>4)*4+reg (HW-verified)
    const int q4 = quad * 4;
#pragma unroll
    for (int i = 0; i < MI; ++i)
#pragma unroll
        for (int j = 0; j < NJ; ++j) {
            const int gcol = col0 + j * 16 + l16;
            const float bj = (MODE == 1 || MODE == 2) ? bias[gcol] : 0.f;
#pragma unroll
            for (int r = 0; r < 4; ++r) {
                const int grow = row0 + i * 16 + q4 + r;
                const size_t idx = (size_t)grow * ldc + gcol;
                const float v = acc[i][j][r];
                if (MODE == 1) {
                    Cf[idx] += v + bj;
                } else if (MODE == 2) {
                    const float u = v + bj;
                    Cb[idx] = f2bf(0.5f * u * (1.f + erff(u * 0.70710678118654752f)));
                } else if (MODE == 3) {
                    Cb[idx] = f2bf(v);
                } else {
                    Cf[idx] = fmaxf(v, 0.f) + cat[(size_t)(grow % LL) * DD + gcol];
                }
            }
        }
}

// ---------------------------------------------------------------------------
// 3b) LDS-staged bf16 MFMA GEMM (R3-proven, measured-best): 128x128 tile,
//     4 waves, BK=64, double-buffered global_load_lds, one __syncthreads per
//     step, k8-chunk-major LDS (0 bank conflicts), XCD chunk-swizzle.
//     MODE 1: Cf += acc + bias (atomicAdd when SPLIT>1; bias only slice 0)
//     MODE 2: Cb = bf16(gelu(acc+bias))
//     MODE 3: Cb = bf16(acc)
// ---------------------------------------------------------------------------
#define GLL(gp, lp) __builtin_amdgcn_global_load_lds(                       \
    (const __attribute__((address_space(1))) void*)(gp),                     \
    (__attribute__((address_space(3))) void*)(lp), 16, 0, 0)

template <int MODE, int SPLIT>
__global__ __launch_bounds__(256)
void gemm_lds(const ushort_t* __restrict__ A, int lda,
              const ushort_t* __restrict__ Bt, int ldb,
              const float* __restrict__ bias,
              float* __restrict__ Cf, ushort_t* __restrict__ Cb,
              int ldc, int K)
{
    __shared__ ushort_t As[2][8192];   // [buf][k8*128*8 + row*8 + e], 128 x 64
    __shared__ ushort_t Bs[2][8192];

    const int t    = threadIdx.x;          // 0..255
    const int wv   = t >> 6;               // wave 0..3 (uniform per wave)
    const int lane = t & 63;
    const int l16  = lane & 15, quad = lane >> 4;
    const int wr   = (wv >> 1) * 64;       // wave's 64x64 quadrant
    const int wc   = (wv & 1) * 64;

    // XCD-swizzled block id
    const int nwg = gridDim.x * gridDim.y * gridDim.z;
    const int bid = blockIdx.x + gridDim.x * (blockIdx.y + gridDim.y * blockIdx.z);
    const int w   = swz_xcd(bid, nwg);
    const int bx  = w % gridDim.x;
    const int byz = w / gridDim.x;
    const int by  = byz % gridDim.y;
    const int bz  = byz / gridDim.y;

    const int row0 = by * 128, col0 = bx * 128;
    const int Kper = K / SPLIT;
    const int k0   = bz * Kper;
    const int steps = Kper / 64;

    const ushort_t* Ag = A  + (size_t)(row0 + (t & 127)) * lda + k0 + ((t >> 7) * 8);
    const ushort_t* Bg = Bt + (size_t)(col0 + (t & 127)) * ldb + k0 + ((t >> 7) * 8);

#define STAGE(c, kk) do {                                                    \
        _Pragma("unroll")                                                    \
        for (int ii = 0; ii < 4; ++ii) {                                     \
            GLL(Ag + (kk) + ii * 16, &As[c][ii * 2048 + wv * 512]);          \
            GLL(Bg + (kk) + ii * 16, &Bs[c][ii * 2048 + wv * 512]);          \
        }                                                                    \
    } while (0)

    f32x4 acc[4][4];
#pragma unroll
    for (int i = 0; i < 4; ++i)
#pragma unroll
        for (int j = 0; j < 4; ++j) {
            acc[i][j][0] = 0.f; acc[i][j][1] = 0.f;
            acc[i][j][2] = 0.f; acc[i][j][3] = 0.f;
        }

    STAGE(0, 0);
    __syncthreads();                       // drains vmcnt(0): buf0 ready
    int cur = 0;
    for (int s = 0; s < steps; ++s) {
        if (s + 1 < steps) STAGE(cur ^ 1, (s + 1) * 64);   // async prefetch
#pragma unroll
        for (int ks = 0; ks < 2; ++ks) {
            bf16x8 af[4], bfr[4];
#pragma unroll
            for (int i = 0; i < 4; ++i)
                af[i] = *reinterpret_cast<const bf16x8*>(
                    &As[cur][((ks * 4 + quad) * 128 + wr + i * 16 + l16) * 8]);
#pragma unroll
            for (int j = 0; j < 4; ++j)
                bfr[j] = *reinterpret_cast<const bf16x8*>(
                    &Bs[cur][((ks * 4 + quad) * 128 + wc + j * 16 + l16) * 8]);
#pragma unroll
            for (int i = 0; i < 4; ++i)
#pragma unroll
                for (int j = 0; j < 4; ++j)
                    acc[i][j] = __builtin_amdgcn_mfma_f32_16x16x32_bf16(
                        af[i], bfr[j], acc[i][j], 0, 0, 0);
        }
        __syncthreads();                   // drains prefetch + guards buf reuse
        cur ^= 1;
    }
#undef STAGE

    // epilogue: C/D layout col=lane&15, row=(lane>>4)*4+reg
    const int q4 = quad * 4;
    const int r0w = row0 + wr, c0w = col0 + wc;
#pragma unroll
    for (int i = 0; i < 4; ++i)
#pragma unroll
        for (int j = 0; j < 4; ++j) {
            const int gcol = c0w + j * 16 + l16;
            const float bj = (MODE == 1 || MODE == 2)
                               ? ((SPLIT == 1 || bz == 0) ? bias[gcol] : 0.f)
                               : 0.f;
#pragma unroll
            for (int r = 0; r < 4; ++r) {
                const int grow = r0w + i * 16 + q4 + r;
                const size_t idx = (size_t)grow * ldc + gcol;
                const float v = acc[i][j][r];
                if (MODE == 1) {
                    if (SPLIT > 1) atomicAdd(&Cf[idx], v + bj);
                    else           Cf[idx] += v + bj;
                } else if (MODE == 2) {
                    const float u = v + bj;
                    Cb[idx] = f2bf(0.5f * u * (1.f + erff(u * 0.70710678118654752f)));
                } else {
                    Cb[idx] = f2bf(v);
                }
            }
        }
}

// ---------------------------------------------------------------------------
// 4) MFMA attention, q-split: block per (half, b*NH+h), 5 waves; each wave
//    handles ONE 16-row q-tile (q0 = half*80 + wave*16).  384 blocks.
// ---------------------------------------------------------------------------
#define KS_STRIDE 72
#define VT_STRIDE 168
__global__ __launch_bounds__(320)
void attention_mfma(ushort_t* __restrict__ qkv)
{
    __shared__ ushort_t Ks[160 * KS_STRIDE];
    __shared__ ushort_t Vt[64 * VT_STRIDE];
    __shared__ ushort_t Pb[5][16 * VT_STRIDE];

    const int half = blockIdx.x;          // 0..1
    const int b  = blockIdx.y / NH;
    const int hh = blockIdx.y % NH;
    ushort_t* basew = qkv + (size_t)b * LL * (3 * DD) + hh * DH;
    const ushort_t* base = basew;
    const int tid  = threadIdx.x;
    const int wave = tid >> 6, lane = tid & 63;
    const int l16 = lane & 15, quad = lane >> 4;

    // ---- stage K rows and V transposed (all 160 kv rows) ----
#pragma unroll
    for (int it = 0; it < 4; ++it) {
        int idx = tid + it * 320;                 // 0..1279
        int l = idx >> 3, c8 = (idx & 7) * 8;
        uint4 kv = *(const uint4*)(base + (size_t)l * (3 * DD) + DD + c8);
        *(uint4*)&Ks[l * KS_STRIDE + c8] = kv;
        uint4 vv = *(const uint4*)(base + (size_t)l * (3 * DD) + 2 * DD + c8);
        ushort_t e[8];
        *(uint4*)e = vv;
#pragma unroll
        for (int i = 0; i < 8; ++i)
            Vt[(c8 + i) * VT_STRIDE + l] = e[i];
    }

    // ---- Q fragments straight from global (one 16-row tile per wave) ----
    const int q0 = half * 80 + wave * 16;
    bf16x8 qf[2];
#pragma unroll
    for (int k = 0; k < 2; ++k)
        qf[k] = *reinterpret_cast<const bf16x8*>(
            base + (size_t)(q0 + l16) * (3 * DD) + k * 32 + quad * 8);

    __syncthreads();

    // ---- S = QK^T ----
    f32x4 S[10];
#pragma unroll
    for (int nt = 0; nt < 10; ++nt) {
        f32x4 z = {0.f, 0.f, 0.f, 0.f};
        const ushort_t* kb = &Ks[(nt * 16 + l16) * KS_STRIDE + quad * 8];
        bf16x8 kf0 = *reinterpret_cast<const bf16x8*>(kb);
        bf16x8 kf1 = *reinterpret_cast<const bf16x8*>(kb + 32);
        f32x4 a0 = __builtin_amdgcn_mfma_f32_16x16x32_bf16(qf[0], kf0, z, 0, 0, 0);
        S[nt]    = __builtin_amdgcn_mfma_f32_16x16x32_bf16(qf[1], kf1, a0, 0, 0, 0);
    }

    // ---- softmax; P (already / l) to wave-private LDS ----
    {
        float mrow[4] = {-1e30f, -1e30f, -1e30f, -1e30f};
#pragma unroll
        for (int nt = 0; nt < 10; ++nt)
#pragma unroll
            for (int r = 0; r < 4; ++r) {
                S[nt][r] *= 0.125f;
                mrow[r] = fmaxf(mrow[r], S[nt][r]);
            }
#pragma unroll
        for (int r = 0; r < 4; ++r) {
            mrow[r] = fmaxf(mrow[r], __shfl_xor(mrow[r], 1));
            mrow[r] = fmaxf(mrow[r], __shfl_xor(mrow[r], 2));
            mrow[r] = fmaxf(mrow[r], __shfl_xor(mrow[r], 4));
            mrow[r] = fmaxf(mrow[r], __shfl_xor(mrow[r], 8));
        }
        float lsum[4] = {0.f, 0.f, 0.f, 0.f};
#pragma unroll
        for (int nt = 0; nt < 10; ++nt)
#pragma unroll
            for (int r = 0; r < 4; ++r) {
                float e = __expf(S[nt][r] - mrow[r]);
                S[nt][r] = e;
                lsum[r] += e;
            }
#pragma unroll
        for (int r = 0; r < 4; ++r) {
            lsum[r] += __shfl_xor(lsum[r], 1);
            lsum[r] += __shfl_xor(lsum[r], 2);
            lsum[r] += __shfl_xor(lsum[r], 4);
            lsum[r] += __shfl_xor(lsum[r], 8);
            lsum[r] = 1.f / lsum[r];
        }
#pragma unroll
        for (int nt = 0; nt < 10; ++nt)
#pragma unroll
            for (int r = 0; r < 4; ++r)
                Pb[wave][(quad * 4 + r) * VT_STRIDE + nt * 16 + l16] =
                    f2bf(S[nt][r] * lsum[r]);
    }
    asm volatile("s_waitcnt lgkmcnt(0)" ::: "memory");   // wave-local P write->read

    // ---- O^T = Vt . P^T ; write into q-slot ----
#pragma unroll
    for (int dt = 0; dt < 4; ++dt) {
        f32x4 o0 = {0.f, 0.f, 0.f, 0.f};
#pragma unroll
        for (int ks = 0; ks < 5; ++ks) {
            bf16x8 vf = *reinterpret_cast<const bf16x8*>(
                &Vt[(dt * 16 + l16) * VT_STRIDE + ks * 32 + quad * 8]);
            bf16x8 p0 = *reinterpret_cast<const bf16x8*>(
                &Pb[wave][(l16) * VT_STRIDE + ks * 32 + quad * 8]);
            o0 = __builtin_amdgcn_mfma_f32_16x16x32_bf16(vf, p0, o0, 0, 0, 0);
        }
        ushort_t pk[4];
#pragma unroll
        for (int r = 0; r < 4; ++r) pk[r] = f2bf(o0[r]);
        ushort_t* dst = basew + (size_t)(q0 + l16) * (3 * DD) + dt * 16 + quad * 4;
        *(uint2*)dst = *(const uint2*)pk;
    }
}

// ---------------------------------------------------------------------------
// 5) mask + grid aggregation + temporal mean, v3: WIDE + register-staged.
//    Block per (b, g, half-row of 7 hw) = 3584 blocks (14/CU queued — real
//    TLP, unlike v2's 512 serial blocks at 65 us).  Each thread keeps its
//    3-d-slice of all 20 feat rows in REGISTERS (60 VGPR, statically
//    indexed via full unroll), so the panel is read from L2 once per block
//    (215 MB aggregate ~ 6 us) instead of 196x (v1) or serialized (v2).
//    hh fixed per block -> y-test folded into an x-sentinel (x1=+2 on fail).
// ---------------------------------------------------------------------------
__global__ __launch_bounds__(256)
void mask_grid(const float* __restrict__ box, const float* __restrict__ feats,
               float* __restrict__ out)
{
    const int bx2 = blockIdx.x;            // 0..27: hh = bx2>>1, w0 = (bx2&1)*7
    const int g = blockIdx.y;
    const int b = blockIdx.z;
    const int hh = bx2 >> 1, w0 = (bx2 & 1) * 7;
    const float cy = (hh + 0.5f) / (float)GH;
    const int tid = threadIdx.x;

    __shared__ float x1s[20], x2s[20];
    if (tid < 20) {
        int t = g * 2 + tid / OO, o = tid % OO;
        const float* bp = box + (size_t)((b * TT + t) * OO + o) * 4;
        float x1 = fminf(bp[0], bp[2]), x2 = fmaxf(bp[0], bp[2]);
        float y1 = fminf(bp[1], bp[3]), y2 = fmaxf(bp[1], bp[3]);
        bool yok = (cy >= y1) && (cy <= y2);
        x1s[tid] = yok ? x1 : 2.f;         // sentinel: x-test always fails
        x2s[tid] = yok ? x2 : -2.f;
    }

    // stage 20 rows x 3 d-chunks into registers (statically indexed)
    float fr[20][3];
#pragma unroll
    for (int p = 0; p < 20; ++p) {
        int r = (b * TT + g * 2 + p / OO) * OO + (p % OO);
        const float* f = feats + (size_t)r * DD;
        fr[p][0] = f[tid];
        fr[p][1] = f[tid + 256];
        fr[p][2] = f[tid + 512];
    }
    __syncthreads();

    float* obase = out + ((size_t)(b * TGRP + g) * (GH * GW) + hh * GW + w0) * DD;
    for (int w = 0; w < 7; ++w) {
        const float cx = (w0 + w + 0.5f) / (float)GW;
        float a0 = 0.f, a1 = 0.f, a2 = 0.f;
#pragma unroll
        for (int p = 0; p < 20; ++p) {
            if (cx >= x1s[p] && cx <= x2s[p]) {
                a0 += fr[p][0]; a1 += fr[p][1]; a2 += fr[p][2];
            }
        }
        float* op = obase + (size_t)w * DD;
        op[tid]       = a0 * 0.5f;
        op[tid + 256] = a1 * 0.5f;
        op[tid + 512] = a2 * 0.5f;
    }
}

// ---------------------------------------------------------------------------
extern "C" void kernel_launch(void* const* d_in, const int* in_sizes, int n_in,
                              void* d_out, int out_size, void* d_ws, size_t ws_size,
                              hipStream_t stream)
{
    const float* box  = (const float*)d_in[0];
    const float* cat  = (const float*)d_in[1];
    const float* w1   = (const float*)d_in[2];
    const float* w2   = (const float*)d_in[3];
    const float* ln1g = (const float*)d_in[4];
    const float* ln1b = (const float*)d_in[5];
    const float* wqkv = (const float*)d_in[6];
    const float* wo   = (const float*)d_in[7];
    const float* bo   = (const float*)d_in[8];
    const float* ln2g = (const float*)d_in[9];
    const float* ln2b = (const float*)d_in[10];
    const float* wfc1 = (const float*)d_in[11];
    const float* bfc1 = (const float*)d_in[12];
    const float* wfc2 = (const float*)d_in[13];
    const float* bfc2 = (const float*)d_in[14];
    float* out = (float*)d_out;

    // workspace layout (byte offsets, 16B aligned), total 44,236,800 B
    char* wsb = (char*)d_ws;
    float*    x     = (float*)   (wsb + 0);           //  7,864,320 (2560x768 f32)
    ushort_t* qkvb  = (ushort_t*)(wsb + 7864320);     // 15,728,640 (qkv 2560x2304 / fc1 2560x3072 overlay)
    ushort_t* fc1b  = qkvb;
    ushort_t* wfc2T = (ushort_t*)(wsb + 23592960);    //  4,718,592 (768x3072)
    ushort_t* hnb   = (ushort_t*)(wsb + 28311552);    //  3,932,160 (2560x768)
    ushort_t* wqkvT = (ushort_t*)(wsb + 32243712);    //  3,538,944 (2304x768)
    ushort_t* woT   = (ushort_t*)(wsb + 35782656);    //  1,179,648 (768x768)
    ushort_t* wfc1T = (ushort_t*)(wsb + 36962304);    //  4,718,592 (3072x768)
    ushort_t* w2T   = (ushort_t*)(wsb + 41680896);    //    589,824 (768x384)
    ushort_t* h     = (ushort_t*)(wsb + 42270720);    //  1,966,080 (2560x384)

    // all prep work (5 transposes + box_h) in ONE wide dispatch
    prep_all<<<11040, 256, 0, stream>>>(wqkv, wo, wfc1, wfc2, w2, box, w1,
                                        wqkvT, woT, wfc1T, wfc2T, w2T, h);
    // x = relu(h @ w2) + cat[t,o]   (64x64 rf, 480 1-wave blocks)
    gemm_rf2<4, 4, 4, 1><<<dim3(12, 40, 1), 64, 0, stream>>>(
        h, 384, w2T, 384, nullptr, cat, x, nullptr, DD, 384);
    ln_kernel<<<BL, 256, 0, stream>>>(x, ln1g, ln1b, hnb);
    // qkv = hn @ wqkv   (360 blocks, 12 steps)
    gemm_lds<3, 1><<<dim3(2304 / 128, 2560 / 128, 1), 256, 0, stream>>>(
        hnb, DD, wqkvT, DD, nullptr, nullptr, qkvb, 3 * DD, DD);
    // attention, q-split: 384 blocks
    attention_mfma<<<dim3(2, BATCH * NH), 320, 0, stream>>>(qkvb);
    // x += attn_out @ wo + bo   (split2, 240 blocks, 6 steps — R3 config)
    gemm_lds<1, 2><<<dim3(768 / 128, 2560 / 128, 2), 256, 0, stream>>>(
        qkvb, 3 * DD, woT, DD, bo, x, nullptr, DD, DD);
    ln_kernel<<<BL, 256, 0, stream>>>(x, ln2g, ln2b, hnb);
    // fc1 = gelu(hn @ wfc1 + bfc1)   (480 blocks, 12 steps)
    gemm_lds<2, 1><<<dim3(3072 / 128, 2560 / 128, 1), 256, 0, stream>>>(
        hnb, DD, wfc1T, DD, bfc1, nullptr, fc1b, 4 * DD, DD);
    // x += gelu_fc1 @ wfc2 + bfc2   (split4, 480 blocks, 12 steps — R3 config)
    gemm_lds<1, 4><<<dim3(768 / 128, 2560 / 128, 4), 256, 0, stream>>>(
        fc1b, 4 * DD, wfc2T, 4 * DD, bfc2, x, nullptr, DD, 4 * DD);
    mask_grid<<<dim3(28, TGRP, BATCH), 256, 0, stream>>>(box, x, out);
}